// Round 16
// baseline (429.323 us; speedup 1.0000x reference)
//
#include <hip/hip_runtime.h>

#define NPTS 8192
#define KSEL 33    // rank 0 (self) + 32 neighbors
#define SCAP 512   // survivor capacity (threshold ~ global rank 100-150; R7 lesson)
#define PPB  32    // points per block
#define NBLK (NPTS / PPB)   // 256 blocks x 512 thr -> 1 block/CU, all resident

typedef float vf4 __attribute__((ext_vector_type(4)));

// LDS-coherent block barrier that does NOT drain vmcnt (raw s_barrier):
// gather stores stay in flight across iterations.
__device__ __forceinline__ void sync_lds() {
    asm volatile("s_waitcnt lgkmcnt(0)" ::: "memory");
    __builtin_amdgcn_s_barrier();
}

// ---------------------------------------------------------------------------
// Prep: pts4[j] = (x, y, z, sq), sq = (x*x + y*y) + z*z in exact reference
// rounding order (contract off, separate mul/add).
// ---------------------------------------------------------------------------
__global__ __launch_bounds__(256) void prep_kernel(const float* __restrict__ pts,
                                                   float4* __restrict__ pts4) {
#pragma clang fp contract(off)
    const int j = blockIdx.x * 256 + threadIdx.x;
    const float x = pts[j * 3 + 0];
    const float y = pts[j * 3 + 1];
    const float z = pts[j * 3 + 2];
    const float sq = (x * x + y * y) + z * z;
    pts4[j] = make_float4(x, y, z, sq);
}

// ---------------------------------------------------------------------------
// Producer-consumer fused kNN + gather. 512 threads = 8 waves:
//   waves 0-3 (select team): R12's select, byte-identical math -> jlist
//     double buffer in LDS. Issues NO global stores, so its pts4 loads never
//     wait behind store drain (round-10 vmcnt-FIFO lesson).
//   waves 4-7 (gather team): R12's read-once/store-many gather for point
//     it-1 while select computes point it. Its loads only queue behind its
//     OWN previous point's stores = runs at write-BW rate by construction.
// 3 raw barriers per iteration (no vmcnt drain), identical count for all
// waves. jlist[b]: write(it) -> read(it+1) -> overwrite(it+2), >=3 barriers
// apart. Output bit-identical to rounds 6/9/12.
// ---------------------------------------------------------------------------
__global__ __launch_bounds__(512) void knn_pc_kernel(const float4* __restrict__ pts4,
                                                     const float* __restrict__ feats,
                                                     float* __restrict__ out) {
#pragma clang fp contract(off)
    const int tid = threadIdx.x;          // 0..511
    const int lane = tid & 63;
    const int wv = tid >> 6;              // 0..7
    const bool selteam = (wv < 4);
    const int gwv = wv - 4;               // gather wave id 0..3

    __shared__ unsigned red[4];
    __shared__ int sh_cnt;
    __shared__ unsigned long long S[SCAP];
    __shared__ unsigned jlist[2][32];

    const unsigned long long O1 = (unsigned long long)NPTS * 256ull;
    const unsigned long long O2 = O1 + (unsigned long long)NPTS * 2048ull;
    const unsigned long long O3 = O2 + (unsigned long long)NPTS * 4096ull;

    for (int it = 0; it <= PPB; ++it) {
        // per-iteration select state (registers live across barriers)
        unsigned d[32];
        unsigned m1 = 0xFFFFFFFFu, m2 = 0xFFFFFFFFu;
        float4 pi;

        // ---------------- Phase A ----------------
        if (selteam && it < PPB) {
            const int i = blockIdx.x * PPB + it;
            pi = pts4[i];
            if (tid == 0) sh_cnt = 0;     // prev readers are past B3(it-1)
#pragma unroll
            for (int t = 0; t < 32; ++t) {
                const int j = tid + t * 256;
                const float4 pj = pts4[j];
                const float dot = __builtin_fmaf(pi.z, pj.z,
                                   __builtin_fmaf(pi.y, pj.y, pi.x * pj.x));
                const float d2 = (pi.w + pj.w) - (2.0f * dot);
                const unsigned db = __float_as_uint(fmaxf(d2, 0.0f));
                d[t] = db;
                const unsigned mx = db > m1 ? db : m1;
                m1 = db < m1 ? db : m1;
                m2 = mx < m2 ? mx : m2;
                if ((t & 7) == 7) __builtin_amdgcn_sched_barrier(0);
            }
            // per-wave ballot binary search: 33rd smallest of {m1,m2}
            unsigned blo = 0u, bhi = 0x7F800000u;
            while (blo < bhi) {
                const unsigned mid = (blo + bhi) >> 1;
                const int cnt = __popcll(__ballot(m1 <= mid)) +
                                __popcll(__ballot(m2 <= mid));
                if (cnt >= KSEL) bhi = mid; else blo = mid + 1u;
            }
            if (lane == 0) red[wv] = bhi;
        }
        if (!selteam && it > 0) {
            // gather point it-1 from jlist[(it-1)&1]
            const unsigned long long ii = (unsigned long long)(blockIdx.x * PPB + (it - 1));
            const unsigned* jl = jlist[(it - 1) & 1];

            vf4 vself;
            if (gwv == 0) vself = ((const vf4*)(feats + ii * 256ull))[lane];
            vf4 vk[8];
#pragma unroll
            for (int m = 0; m < 8; ++m) {
                const unsigned src = jl[gwv + 4 * m];
                vk[m] = ((const vf4*)(feats + (unsigned long long)src * 256ull))[lane];
            }
            if (gwv == 0)
                __builtin_nontemporal_store(vself, &((vf4*)(out + ii * 256ull))[lane]);
#pragma unroll
            for (int m = 0; m < 8; ++m) {
                const unsigned k = (unsigned)(gwv + 4 * m);
                const vf4 v = vk[m];
                __builtin_nontemporal_store(v,
                    &((vf4*)(out + O3 + ii * 8192ull + (unsigned long long)k * 256ull))[lane]);
                if (k < 16u)
                    __builtin_nontemporal_store(v,
                        &((vf4*)(out + O2 + ii * 4096ull + (unsigned long long)k * 256ull))[lane]);
                if (k < 8u)
                    __builtin_nontemporal_store(v,
                        &((vf4*)(out + O1 + ii * 2048ull + (unsigned long long)k * 256ull))[lane]);
            }
        }
        sync_lds();                                   // B1: red ready

        // ---------------- Phase B (select only) ----------------
        if (selteam && it < PPB) {
            unsigned T = red[0];
            T = red[1] < T ? red[1] : T;
            T = red[2] < T ? red[2] : T;
            T = red[3] < T ? red[3] : T;
            const float s = sqrtf(__uint_as_float(T));            // CR sqrt
            const float snx = __uint_as_float(__float_as_uint(s) + 1u);
            const unsigned T2 = __float_as_uint(__fmul_rn(snx, snx)) + 2u;

            int n = 0;
#pragma unroll
            for (int t = 0; t < 32; ++t) n += (d[t] <= T2) ? 1 : 0;
            int incl = n;
#pragma unroll
            for (int sh = 1; sh < 64; sh <<= 1) {
                const int o = __shfl_up(incl, sh, 64);
                if (lane >= sh) incl += o;
            }
            int base = 0;
            if (lane == 63) base = atomicAdd(&sh_cnt, incl);
            base = __shfl(base, 63, 64);
            int ptr = base + incl - n;
#pragma unroll
            for (int t = 0; t < 32; ++t) {
                if (d[t] <= T2) {
                    const unsigned db = __float_as_uint(sqrtf(__uint_as_float(d[t])));
                    if (ptr < SCAP)
                        S[ptr] = (((unsigned long long)db) << 32) | (unsigned)(tid + t * 256);
                    ++ptr;
                }
            }
        }
        sync_lds();                                   // B2: S ready

        // ---------------- Phase C (select only) ----------------
        if (selteam && it < PPB) {
            const int c = sh_cnt < SCAP ? sh_cnt : SCAP;
            for (int q = tid; q < c; q += 256) {
                const unsigned long long key = S[q];
                int rank = 0;
                for (int u = 0; u < c; ++u) rank += (S[u] < key) ? 1 : 0;
                if (rank >= 1 && rank < KSEL) jlist[it & 1][rank - 1] = (unsigned)key;
            }
        }
        sync_lds();                                   // B3: jlist(it) ready
    }
}

extern "C" void kernel_launch(void* const* d_in, const int* in_sizes, int n_in,
                              void* d_out, int out_size, void* d_ws, size_t ws_size,
                              hipStream_t stream) {
    const float* feats = (const float*)d_in[0];   // (8192, 256) f32
    const float* pts = (const float*)d_in[1];     // (8192, 3)   f32
    // d_in[2] = f_masks (all ones; unused by the reference computation)

    float4* pts4 = (float4*)d_ws;                 // 128 KB scratch

    prep_kernel<<<NPTS / 256, 256, 0, stream>>>(pts, pts4);
    knn_pc_kernel<<<NBLK, 512, 0, stream>>>(pts4, feats, (float*)d_out);
}

// Round 17
// 156.387 us; speedup vs baseline: 2.7453x; 2.7453x over previous
//
#include <hip/hip_runtime.h>

#define NPTS 8192
#define KSEL 33    // rank 0 (self) + 32 neighbors
#define SCAP 512   // survivor capacity (threshold ~ global rank 100-150; R7 lesson)

typedef float vf4 __attribute__((ext_vector_type(4)));

// ---------------------------------------------------------------------------
// Prep: pts4[j] = (x, y, z, sq), sq = (x*x + y*y) + z*z in exact reference
// rounding order (contract off, separate mul/add).
// ---------------------------------------------------------------------------
__global__ __launch_bounds__(256) void prep_kernel(const float* __restrict__ pts,
                                                   float4* __restrict__ pts4) {
#pragma clang fp contract(off)
    const int j = blockIdx.x * 256 + threadIdx.x;
    const float x = pts[j * 3 + 0];
    const float y = pts[j * 3 + 1];
    const float z = pts[j * 3 + 2];
    const float sq = (x * x + y * y) + z * z;
    pts4[j] = make_float4(x, y, z, sq);
}

// ---------------------------------------------------------------------------
// Fused exact-kNN + gather: R12 structure (block-per-point, 4 waves, natural
// cross-block select/gather overlap — every alternative structure in rounds
// 13-16 regressed). This round's single change: d[32] moved from VGPRs to
// LDS (d_lds[t][tid], thread-private slots, bank = tid%32 -> only 2-way
// aliasing = free). Removes ~32 VGPRs: measured 132 VGPR = 2 waves/SIMD bin;
// <=128 doubles to 4 waves/SIMD -> 4 blocks/CU co-resident (R11 showed
// forcing this via launch_bounds spills; this is the organic route).
// LDS/block: 32KB (d) + 4KB (S) + misc = 36.3KB -> 4 blocks/CU fits.
//
// Selection math byte-identical to rounds 6/9/12 (bit-identical output):
//   exact reference d2 bits -> per-thread 2-min -> per-wave ballot binary
//   search (33rd of the 128-value {m1,m2} multiset = safe upper bound) ->
//   min over waves -> CR-sqrt closure widen -> compact survivors (CR sqrt
//   only there) -> all-pairs rank on (dist<<32|j) = lax.top_k order.
// Gather: read-once / store-many (out1/out2 rows are prefixes of out3's),
// 8 up-front row loads per wave, NT float4 stores.
// ---------------------------------------------------------------------------
__global__ __launch_bounds__(256) void knn_fused_kernel(const float4* __restrict__ pts4,
                                                        const float* __restrict__ feats,
                                                        float* __restrict__ out) {
#pragma clang fp contract(off)
    const int i = blockIdx.x;
    const int tid = threadIdx.x;
    const int lane = tid & 63;
    const int wv = tid >> 6;

    __shared__ unsigned red[4];
    __shared__ int sh_cnt;
    __shared__ unsigned long long S[SCAP];
    __shared__ unsigned jlist[32];
    __shared__ unsigned d_lds[32][256];   // d2 bits, [t][tid]: thread-private

    const float4 pi = pts4[i];

    unsigned m1 = 0xFFFFFFFFu, m2 = 0xFFFFFFFFu;
#pragma unroll
    for (int t = 0; t < 32; ++t) {
        const int j = tid + t * 256;
        const float4 pj = pts4[j];
        const float dot = __builtin_fmaf(pi.z, pj.z, __builtin_fmaf(pi.y, pj.y, pi.x * pj.x));
        const float d2 = (pi.w + pj.w) - (2.0f * dot);
        const unsigned db = __float_as_uint(fmaxf(d2, 0.0f));
        d_lds[t][tid] = db;
        const unsigned mx = db > m1 ? db : m1;   // max(db, m1)
        m1 = db < m1 ? db : m1;                  // min
        m2 = mx < m2 ? mx : m2;                  // 2nd smallest
        if ((t & 7) == 7) __builtin_amdgcn_sched_barrier(0);  // cap in-flight loads
    }
    if (tid == 0) sh_cnt = 0;

    // --- per-wave ballot binary search: exact 33rd smallest of {m1,m2} ---
    unsigned blo = 0u, bhi = 0x7F800000u;        // finite non-neg float bits
    while (blo < bhi) {
        const unsigned mid = (blo + bhi) >> 1;
        const int cnt = __popcll(__ballot(m1 <= mid)) + __popcll(__ballot(m2 <= mid));
        if (cnt >= KSEL) bhi = mid; else blo = mid + 1u;
    }
    if (lane == 0) red[wv] = bhi;
    __syncthreads();
    unsigned T = red[0];
    T = red[1] < T ? red[1] : T;
    T = red[2] < T ? red[2] : T;
    T = red[3] < T ? red[3] : T;

    // --- widen to sqrt-closure (conservative, provably inclusive) ---
    const float s = sqrtf(__uint_as_float(T));               // CR sqrt
    const float snx = __uint_as_float(__float_as_uint(s) + 1u);
    const unsigned T2 = __float_as_uint(__fmul_rn(snx, snx)) + 2u;

    // --- compact survivors into LDS (CR sqrt only here) ---
    int n = 0;
#pragma unroll
    for (int t = 0; t < 32; ++t) n += (d_lds[t][tid] <= T2) ? 1 : 0;

    int incl = n;
#pragma unroll
    for (int sh = 1; sh < 64; sh <<= 1) {
        const int o = __shfl_up(incl, sh, 64);
        if (lane >= sh) incl += o;
    }
    int base = 0;
    if (lane == 63) base = atomicAdd(&sh_cnt, incl);
    base = __shfl(base, 63, 64);
    int ptr = base + incl - n;
#pragma unroll
    for (int t = 0; t < 32; ++t) {
        const unsigned dv = d_lds[t][tid];
        if (dv <= T2) {
            const unsigned db = __float_as_uint(sqrtf(__uint_as_float(dv)));
            if (ptr < SCAP)
                S[ptr] = (((unsigned long long)db) << 32) | (unsigned)(tid + t * 256);
            ++ptr;
        }
    }
    __syncthreads();

    // --- exact global rank among survivors (keys unique via j) ---
    const int c = sh_cnt < SCAP ? sh_cnt : SCAP;
    for (int q = tid; q < c; q += 256) {
        const unsigned long long key = S[q];
        int rank = 0;
        for (int u = 0; u < c; ++u) rank += (S[u] < key) ? 1 : 0;
        if (rank >= 1 && rank < KSEL) jlist[rank - 1] = (unsigned)key;
    }
    __syncthreads();

    // --- gather: read-once / store-many ---
    const unsigned long long O1 = (unsigned long long)NPTS * 256ull;
    const unsigned long long O2 = O1 + (unsigned long long)NPTS * 2048ull;
    const unsigned long long O3 = O2 + (unsigned long long)NPTS * 4096ull;
    const unsigned long long ii = (unsigned long long)i;

    // issue all row-reads first (8 neighbor rows per wave, + self on wave 0)
    vf4 vself;
    if (wv == 0) {
        const vf4* sp = (const vf4*)(feats + ii * 256ull);
        vself = sp[lane];
    }
    vf4 vk[8];
    unsigned kk[8];
#pragma unroll
    for (int m = 0; m < 8; ++m) {
        const int k = wv + 4 * m;
        const unsigned src = jlist[k];
        kk[m] = (unsigned)k;
        const vf4* sp = (const vf4*)(feats + (unsigned long long)src * 256ull);
        vk[m] = sp[lane];
    }

    // stores: out3 always; mirror to out2 (k<16) and out1 (k<8)
    if (wv == 0) {
        __builtin_nontemporal_store(vself, &((vf4*)(out + ii * 256ull))[lane]);
    }
#pragma unroll
    for (int m = 0; m < 8; ++m) {
        const unsigned k = kk[m];
        const vf4 v = vk[m];
        __builtin_nontemporal_store(v,
            &((vf4*)(out + O3 + ii * 8192ull + (unsigned long long)k * 256ull))[lane]);
        if (k < 16u)
            __builtin_nontemporal_store(v,
                &((vf4*)(out + O2 + ii * 4096ull + (unsigned long long)k * 256ull))[lane]);
        if (k < 8u)
            __builtin_nontemporal_store(v,
                &((vf4*)(out + O1 + ii * 2048ull + (unsigned long long)k * 256ull))[lane]);
    }
}

extern "C" void kernel_launch(void* const* d_in, const int* in_sizes, int n_in,
                              void* d_out, int out_size, void* d_ws, size_t ws_size,
                              hipStream_t stream) {
    const float* feats = (const float*)d_in[0];   // (8192, 256) f32
    const float* pts = (const float*)d_in[1];     // (8192, 3)   f32
    // d_in[2] = f_masks (all ones; unused by the reference computation)

    float4* pts4 = (float4*)d_ws;                 // 128 KB scratch

    prep_kernel<<<NPTS / 256, 256, 0, stream>>>(pts, pts4);
    knn_fused_kernel<<<NPTS, 256, 0, stream>>>(pts4, feats, (float*)d_out);
}

// Round 18
// 149.093 us; speedup vs baseline: 2.8796x; 1.0489x over previous
//
#include <hip/hip_runtime.h>

#define NPTS 8192
#define KSEL 33    // rank 0 (self) + 32 neighbors
#define SCAP 512   // survivor capacity (per-wave 33rd-of-2048-sample threshold
                   // lands at global rank ~100-150; 128 was too small (round 7))

typedef float vf4 __attribute__((ext_vector_type(4)));

// ---------------------------------------------------------------------------
// Prep: pts4[j] = (x, y, z, sq), sq = (x*x + y*y) + z*z in exact reference
// rounding order (contract off, separate mul/add).
// ---------------------------------------------------------------------------
__global__ __launch_bounds__(256) void prep_kernel(const float* __restrict__ pts,
                                                   float4* __restrict__ pts4) {
#pragma clang fp contract(off)
    const int j = blockIdx.x * 256 + threadIdx.x;
    const float x = pts[j * 3 + 0];
    const float y = pts[j * 3 + 1];
    const float z = pts[j * 3 + 2];
    const float sq = (x * x + y * y) + z * z;
    pts4[j] = make_float4(x, y, z, sq);
}

// ---------------------------------------------------------------------------
// Fused exact-kNN + gather — the round-12 champion (149.5 us), restored
// verbatim. Block-per-point, 4 waves; cross-block scheduler mixing provides
// select/gather overlap (12 structural alternatives all regressed:
// QB=8 177, split 198, launch_bounds 177, 8-wave 172, wave-per-point 166,
// persistent 368, producer-consumer 429, d-in-LDS 156).
//
// Selection math bit-identical to the verified chain (rounds 6/9/12):
//   exact reference d2 bits (dot = fma(z,z',fma(y,y',x*x')),
//   d2 = (sq_i+sq_j) - 2*dot, clamped) -> per-thread 2-min ->
//   per-wave ballot binary search (33rd of the 128-value {m1,m2} multiset,
//   safe upper bound on the global 33rd d2) -> min over waves ->
//   CR-sqrt closure widen (non-survivors strictly above the 33rd dist even
//   under tie-break) -> compact survivors (CR sqrt only there) ->
//   all-pairs rank on (dist<<32|j) = lax.top_k (dist, index) order.
// sched_barrier(0) every 8 dist iters caps in-flight loads (VGPR pressure)
// without partial-unroll scratch.
// Gather: read-once / store-many (out1/out2 rows are prefixes of out3's),
// 8 up-front row loads per wave, NT float4 stores.
// ---------------------------------------------------------------------------
__global__ __launch_bounds__(256) void knn_fused_kernel(const float4* __restrict__ pts4,
                                                        const float* __restrict__ feats,
                                                        float* __restrict__ out) {
#pragma clang fp contract(off)
    const int i = blockIdx.x;
    const int tid = threadIdx.x;
    const int lane = tid & 63;
    const int wv = tid >> 6;

    __shared__ unsigned red[4];
    __shared__ int sh_cnt;
    __shared__ unsigned long long S[SCAP];
    __shared__ unsigned jlist[32];

    const float4 pi = pts4[i];

    unsigned d[32];                       // clamped-d2 bits per owned j
    unsigned m1 = 0xFFFFFFFFu, m2 = 0xFFFFFFFFu;
#pragma unroll
    for (int t = 0; t < 32; ++t) {
        const int j = tid + t * 256;
        const float4 pj = pts4[j];
        const float dot = __builtin_fmaf(pi.z, pj.z, __builtin_fmaf(pi.y, pj.y, pi.x * pj.x));
        const float d2 = (pi.w + pj.w) - (2.0f * dot);
        const unsigned db = __float_as_uint(fmaxf(d2, 0.0f));
        d[t] = db;
        const unsigned mx = db > m1 ? db : m1;   // max(db, m1)
        m1 = db < m1 ? db : m1;                  // min
        m2 = mx < m2 ? mx : m2;                  // 2nd smallest
        // scheduling fence every 8 iters: limits in-flight loads (VGPR cap)
        if ((t & 7) == 7) __builtin_amdgcn_sched_barrier(0);
    }
    if (tid == 0) sh_cnt = 0;

    // --- per-wave ballot binary search: exact 33rd smallest of {m1,m2} ---
    unsigned blo = 0u, bhi = 0x7F800000u;        // finite non-neg float bits
    while (blo < bhi) {
        const unsigned mid = (blo + bhi) >> 1;
        const int cnt = __popcll(__ballot(m1 <= mid)) + __popcll(__ballot(m2 <= mid));
        if (cnt >= KSEL) bhi = mid; else blo = mid + 1u;
    }
    if (lane == 0) red[wv] = bhi;
    __syncthreads();
    unsigned T = red[0];
    T = red[1] < T ? red[1] : T;
    T = red[2] < T ? red[2] : T;
    T = red[3] < T ? red[3] : T;

    // --- widen to sqrt-closure (conservative, provably inclusive) ---
    const float s = sqrtf(__uint_as_float(T));               // CR sqrt
    const float snx = __uint_as_float(__float_as_uint(s) + 1u);
    const unsigned T2 = __float_as_uint(__fmul_rn(snx, snx)) + 2u;

    // --- compact survivors into LDS (CR sqrt only here) ---
    int n = 0;
#pragma unroll
    for (int t = 0; t < 32; ++t) n += (d[t] <= T2) ? 1 : 0;

    int incl = n;
#pragma unroll
    for (int sh = 1; sh < 64; sh <<= 1) {
        const int o = __shfl_up(incl, sh, 64);
        if (lane >= sh) incl += o;
    }
    int base = 0;
    if (lane == 63) base = atomicAdd(&sh_cnt, incl);
    base = __shfl(base, 63, 64);
    int ptr = base + incl - n;
#pragma unroll
    for (int t = 0; t < 32; ++t) {
        if (d[t] <= T2) {
            const unsigned db = __float_as_uint(sqrtf(__uint_as_float(d[t])));
            if (ptr < SCAP)
                S[ptr] = (((unsigned long long)db) << 32) | (unsigned)(tid + t * 256);
            ++ptr;
        }
    }
    __syncthreads();

    // --- exact global rank among survivors (keys unique via j) ---
    const int c = sh_cnt < SCAP ? sh_cnt : SCAP;
    for (int q = tid; q < c; q += 256) {
        const unsigned long long key = S[q];
        int rank = 0;
        for (int u = 0; u < c; ++u) rank += (S[u] < key) ? 1 : 0;
        if (rank >= 1 && rank < KSEL) jlist[rank - 1] = (unsigned)key;
    }
    __syncthreads();

    // --- gather: read-once / store-many ---
    const unsigned long long O1 = (unsigned long long)NPTS * 256ull;
    const unsigned long long O2 = O1 + (unsigned long long)NPTS * 2048ull;
    const unsigned long long O3 = O2 + (unsigned long long)NPTS * 4096ull;
    const unsigned long long ii = (unsigned long long)i;

    // issue all row-reads first (8 neighbor rows per wave, + self on wave 0)
    vf4 vself;
    if (wv == 0) {
        const vf4* sp = (const vf4*)(feats + ii * 256ull);
        vself = sp[lane];
    }
    vf4 vk[8];
    unsigned kk[8];
#pragma unroll
    for (int m = 0; m < 8; ++m) {
        const int k = wv + 4 * m;
        const unsigned src = jlist[k];
        kk[m] = (unsigned)k;
        const vf4* sp = (const vf4*)(feats + (unsigned long long)src * 256ull);
        vk[m] = sp[lane];
    }

    // stores: out3 always; mirror to out2 (k<16) and out1 (k<8)
    if (wv == 0) {
        __builtin_nontemporal_store(vself, &((vf4*)(out + ii * 256ull))[lane]);
    }
#pragma unroll
    for (int m = 0; m < 8; ++m) {
        const unsigned k = kk[m];
        const vf4 v = vk[m];
        __builtin_nontemporal_store(v,
            &((vf4*)(out + O3 + ii * 8192ull + (unsigned long long)k * 256ull))[lane]);
        if (k < 16u)
            __builtin_nontemporal_store(v,
                &((vf4*)(out + O2 + ii * 4096ull + (unsigned long long)k * 256ull))[lane]);
        if (k < 8u)
            __builtin_nontemporal_store(v,
                &((vf4*)(out + O1 + ii * 2048ull + (unsigned long long)k * 256ull))[lane]);
    }
}

extern "C" void kernel_launch(void* const* d_in, const int* in_sizes, int n_in,
                              void* d_out, int out_size, void* d_ws, size_t ws_size,
                              hipStream_t stream) {
    const float* feats = (const float*)d_in[0];   // (8192, 256) f32
    const float* pts = (const float*)d_in[1];     // (8192, 3)   f32
    // d_in[2] = f_masks (all ones; unused by the reference computation)

    float4* pts4 = (float4*)d_ws;                 // 128 KB scratch

    prep_kernel<<<NPTS / 256, 256, 0, stream>>>(pts, pts4);
    knn_fused_kernel<<<NPTS, 256, 0, stream>>>(pts4, feats, (float*)d_out);
}